// Round 5
// baseline (4123.060 us; speedup 1.0000x reference)
//
#include <hip/hip_runtime.h>

#define DPDIM 32         // path/link state dim
#define GCOLS 96         // 3*DPDIM gate columns
#define PLEN 8
#define T_ITERS 8
#define RUNITS 256

// ---------------- fast activations (v_exp_f32 + v_rcp_f32) ----------------
__device__ __forceinline__ float fast_sigmoid(float a) {
    return __builtin_amdgcn_rcpf(1.0f + __expf(-a));
}
__device__ __forceinline__ float fast_tanh(float a) {
    return 1.0f - 2.0f * __builtin_amdgcn_rcpf(1.0f + __expf(2.0f * a));
}

#define ACC4F(A, s, V) \
    A.x = fmaf((s), (V).x, A.x); A.y = fmaf((s), (V).y, A.y); \
    A.z = fmaf((s), (V).z, A.z); A.w = fmaf((s), (V).w, A.w);

// ---------------- init states ----------------
__global__ __launch_bounds__(256) void init_kernel(
    const float* __restrict__ traffic, const float* __restrict__ packets,
    const float* __restrict__ eqlam, const float* __restrict__ avgpkt,
    const float* __restrict__ capacity, const float* __restrict__ queues,
    float* __restrict__ path_state, float* __restrict__ link_state,
    int n_paths, int n_links)
{
    int i = blockIdx.x * 256 + threadIdx.x;
    if (i < n_paths) {
        float4* row = (float4*)(path_state + (size_t)i * DPDIM);
        row[0] = make_float4(traffic[i], packets[i], eqlam[i], avgpkt[i]);
        float4 z = make_float4(0.f, 0.f, 0.f, 0.f);
        #pragma unroll
        for (int k = 1; k < 8; ++k) row[k] = z;
    }
    if (i < n_links) {
        float4* row = (float4*)(link_state + (size_t)i * DPDIM);
        row[0] = make_float4(capacity[i], queues[i], 0.f, 0.f);
        float4 z = make_float4(0.f, 0.f, 0.f, 0.f);
        #pragma unroll
        for (int k = 1; k < 8; ++k) row[k] = z;
    }
}

// ---------------- weight transpose: W[k][96] -> WT[jb][k][12] --------------
__global__ __launch_bounds__(256) void transpose_w_kernel(
    const float* __restrict__ W, float* __restrict__ WT)
{
    int i = blockIdx.x * 256 + threadIdx.x;
    if (i >= 8*32*12) return;
    int idx = i % 12;
    int k   = (i / 12) % 32;
    int jb  = i / (12*32);
    int gate = idx >> 2, c = idx & 3;
    WT[i] = W[k*GCOLS + gate*32 + jb*4 + c];
}

// ---------------- CSR build ----------------
__global__ __launch_bounds__(256) void zero_counts_kernel(int* __restrict__ counts, int n) {
    int i = blockIdx.x * 256 + threadIdx.x;
    if (i < n) counts[i] = 0;
}
__global__ __launch_bounds__(256) void hist_kernel(
    const int* __restrict__ link_to_path, int* __restrict__ counts, int n) {
    int i = blockIdx.x * 256 + threadIdx.x;
    if (i < n) atomicAdd(&counts[link_to_path[i]], 1);
}
__global__ __launch_bounds__(1024) void scan_kernel(
    const int* __restrict__ counts, int* __restrict__ offsets,
    int* __restrict__ cursor, int n)
{
    __shared__ int s[1024];
    int t = threadIdx.x;
    int chunk = (n + 1023) >> 10;
    int lo = t * chunk;
    int hi = lo + chunk; if (hi > n) hi = n;
    int local = 0;
    for (int i = lo; i < hi; ++i) local += counts[i];
    s[t] = local;
    __syncthreads();
    for (int d = 1; d < 1024; d <<= 1) {
        int v = (t >= d) ? s[t - d] : 0;
        __syncthreads();
        s[t] += v;
        __syncthreads();
    }
    int base = (t > 0) ? s[t - 1] : 0;
    for (int i = lo; i < hi; ++i) {
        offsets[i] = base; cursor[i] = base; base += counts[i];
    }
    if (t == 1023) offsets[n] = s[1023];
}
__global__ __launch_bounds__(256) void fill_kernel(
    const int* __restrict__ link_to_path, int* __restrict__ cursor,
    int* __restrict__ entries, int n) {
    int e = blockIdx.x * 256 + threadIdx.x;
    if (e < n) {
        int l = link_to_path[e];
        int pos = atomicAdd(&cursor[l], 1);
        entries[pos] = e >> 3;   // path id (PLEN == 8)
    }
}

// ---------------- gate precompute (paths): G = ls@Wp + bip (+bhp for z,r) --
__global__ __launch_bounds__(64) void gate_pre_kernel(
    const float* __restrict__ X, const float* __restrict__ WT,
    const float* __restrict__ bi, const float* __restrict__ bh,
    float* __restrict__ G, int* __restrict__ nzf, int n)
{
    int i = blockIdx.x * 64 + threadIdx.x;
    if (i >= n) return;
    float x[DPDIM];
    bool nz = false;
    const float4* row = (const float4*)(X + (size_t)i * DPDIM);
    #pragma unroll
    for (int k4 = 0; k4 < 8; ++k4) {
        float4 v = row[k4];
        x[4*k4+0]=v.x; x[4*k4+1]=v.y; x[4*k4+2]=v.z; x[4*k4+3]=v.w;
        nz = nz || (v.x != 0.f) || (v.y != 0.f) || (v.z != 0.f) || (v.w != 0.f);
    }
    float* Gp = G + (size_t)i * GCOLS;
    #pragma unroll 1
    for (int jb = 0; jb < 8; ++jb) {
        float4 az = {0.f,0.f,0.f,0.f}, ar = {0.f,0.f,0.f,0.f}, ah = {0.f,0.f,0.f,0.f};
        const float* w = WT + jb*(32*12);
        #pragma unroll
        for (int k = 0; k < DPDIM; ++k) {
            const float xk = x[k];
            ACC4F(az, xk, *(const float4*)(w));
            ACC4F(ar, xk, *(const float4*)(w + 4));
            ACC4F(ah, xk, *(const float4*)(w + 8));
            w += 12;
        }
        const float4 bz = *(const float4*)(bi + jb*4);
        const float4 br = *(const float4*)(bi + 32 + jb*4);
        const float4 bhi = *(const float4*)(bi + 64 + jb*4);
        const float4 cz = *(const float4*)(bh + jb*4);
        const float4 cr = *(const float4*)(bh + 32 + jb*4);
        *(float4*)(Gp + jb*4)      = make_float4(az.x+bz.x+cz.x, az.y+bz.y+cz.y,
                                                 az.z+bz.z+cz.z, az.w+bz.w+cz.w);
        *(float4*)(Gp + 32 + jb*4) = make_float4(ar.x+br.x+cr.x, ar.y+br.y+cr.y,
                                                 ar.z+br.z+cr.z, ar.w+br.w+cr.w);
        *(float4*)(Gp + 64 + jb*4) = make_float4(ah.x+bhi.x, ah.y+bhi.y,
                                                 ah.z+bhi.z, ah.w+bhi.w);
    }
    nzf[i] = nz ? 1 : 0;
}

// ---------------- path GRU: h fully in registers, jb unrolled --------------
__global__ __launch_bounds__(64, 1) void path_kernel(
    const float* __restrict__ Gi, const int* __restrict__ nzf,
    float* __restrict__ path_state, const int* __restrict__ link_to_path,
    const float* __restrict__ UpT, const float* __restrict__ bhp, int n_paths)
{
    int t = threadIdx.x;
    int p = blockIdx.x * 64 + t;
    bool act = p < n_paths;
    int pp = act ? p : (n_paths - 1);
    float h[DPDIM];
    {
        const float4* row = (const float4*)(path_state + (size_t)pp * DPDIM);
        #pragma unroll
        for (int k4 = 0; k4 < 8; ++k4) {
            float4 v = row[k4];
            h[4*k4+0]=v.x; h[4*k4+1]=v.y; h[4*k4+2]=v.z; h[4*k4+3]=v.w;
        }
    }
    int l = link_to_path[pp*PLEN];
    #pragma unroll 1
    for (int s = 0; s < PLEN; ++s) {
        int l_next = (s+1 < PLEN) ? link_to_path[pp*PLEN + s + 1] : 0;
        bool nz = act && (nzf[l] != 0);
        const float* G = Gi + (size_t)l * GCOLS;
        float hn[DPDIM];
        #pragma unroll
        for (int jb = 0; jb < 8; ++jb) {
            const float4 giz = *(const float4*)(G + jb*4);
            const float4 gir = *(const float4*)(G + 32 + jb*4);
            const float4 gih = *(const float4*)(G + 64 + jb*4);
            float4 az = {0.f,0.f,0.f,0.f}, ar = {0.f,0.f,0.f,0.f}, ah = {0.f,0.f,0.f,0.f};
            const float* w = UpT + jb*(32*12);
            #pragma unroll
            for (int k = 0; k < DPDIM; ++k) {
                ACC4F(az, h[k], *(const float4*)(w));
                ACC4F(ar, h[k], *(const float4*)(w + 4));
                ACC4F(ah, h[k], *(const float4*)(w + 8));
                w += 12;
            }
            const float4 bhh = *(const float4*)(bhp + 64 + jb*4);   // uniform
#define PWC(C, j) { \
            float zz = fast_sigmoid(az.C + giz.C); \
            float rr = fast_sigmoid(ar.C + gir.C); \
            float cc = fast_tanh(gih.C + rr * (ah.C + bhh.C)); \
            float ho = h[jb*4+j]; \
            hn[jb*4+j] = nz ? (cc + zz * (ho - cc)) : ho; }
            PWC(x, 0) PWC(y, 1) PWC(z, 2) PWC(w, 3)
#undef PWC
        }
        #pragma unroll
        for (int j = 0; j < DPDIM; ++j) h[j] = hn[j];
        l = l_next;
    }
    if (act) {
        float4* row = (float4*)(path_state + (size_t)p * DPDIM);
        #pragma unroll
        for (int k4 = 0; k4 < 8; ++k4)
            row[k4] = make_float4(h[4*k4+0], h[4*k4+1], h[4*k4+2], h[4*k4+3]);
    }
}

// ---------------- segment sum: path states -> per-link sums ----------------
__global__ __launch_bounds__(256) void seg_sum_kernel(
    const float* __restrict__ path_state, const int* __restrict__ offsets,
    const int* __restrict__ entries, float* __restrict__ path_sum, int n_links)
{
    int t = threadIdx.x;
    int d = t & 31, li = t >> 5;        // 8 links per block, 32 dims each
    int l = blockIdx.x * 8 + li;
    if (l >= n_links) return;
    int beg = offsets[l], end = offsets[l+1];
    float a0 = 0.f, a1 = 0.f, a2 = 0.f, a3 = 0.f;
    int q = beg;
    for (; q + 3 < end; q += 4) {
        int p0 = entries[q], p1 = entries[q+1], p2 = entries[q+2], p3 = entries[q+3];
        a0 += path_state[(size_t)p0 * DPDIM + d];
        a1 += path_state[(size_t)p1 * DPDIM + d];
        a2 += path_state[(size_t)p2 * DPDIM + d];
        a3 += path_state[(size_t)p3 * DPDIM + d];
    }
    for (; q < end; ++q)
        a0 += path_state[(size_t)entries[q] * DPDIM + d];
    path_sum[(size_t)l * DPDIM + d] = (a0 + a1) + (a2 + a3);
}

// ---------------- fused link GRU: gi = x@Wl+bil, gh = h@Ul+bhl, update -----
__global__ __launch_bounds__(64, 1) void link_kernel(
    const float* __restrict__ path_sum, float* __restrict__ link_state,
    const float* __restrict__ WlT, const float* __restrict__ UlT,
    const float* __restrict__ bil, const float* __restrict__ bhl, int n)
{
    int i = blockIdx.x * 64 + threadIdx.x;
    if (i >= n) return;
    float x[DPDIM], h[DPDIM], hn[DPDIM];
    {
        const float4* xrow = (const float4*)(path_sum + (size_t)i * DPDIM);
        const float4* hrow = (const float4*)(link_state + (size_t)i * DPDIM);
        #pragma unroll
        for (int k4 = 0; k4 < 8; ++k4) {
            float4 u = xrow[k4];
            x[4*k4+0]=u.x; x[4*k4+1]=u.y; x[4*k4+2]=u.z; x[4*k4+3]=u.w;
            float4 v = hrow[k4];
            h[4*k4+0]=v.x; h[4*k4+1]=v.y; h[4*k4+2]=v.z; h[4*k4+3]=v.w;
        }
    }
    #pragma unroll
    for (int jb = 0; jb < 8; ++jb) {
        float4 axz = {0.f,0.f,0.f,0.f}, axr = {0.f,0.f,0.f,0.f}, axh = {0.f,0.f,0.f,0.f};
        float4 ahz = {0.f,0.f,0.f,0.f}, ahr = {0.f,0.f,0.f,0.f}, ahh = {0.f,0.f,0.f,0.f};
        const float* wl = WlT + jb*(32*12);
        const float* ul = UlT + jb*(32*12);
        #pragma unroll
        for (int k = 0; k < DPDIM; ++k) {
            ACC4F(axz, x[k], *(const float4*)(wl));
            ACC4F(axr, x[k], *(const float4*)(wl + 4));
            ACC4F(axh, x[k], *(const float4*)(wl + 8));
            ACC4F(ahz, h[k], *(const float4*)(ul));
            ACC4F(ahr, h[k], *(const float4*)(ul + 4));
            ACC4F(ahh, h[k], *(const float4*)(ul + 8));
            wl += 12; ul += 12;
        }
        const float4 bz = *(const float4*)(bil + jb*4);
        const float4 br = *(const float4*)(bil + 32 + jb*4);
        const float4 bhi = *(const float4*)(bil + 64 + jb*4);
        const float4 cz = *(const float4*)(bhl + jb*4);
        const float4 cr = *(const float4*)(bhl + 32 + jb*4);
        const float4 ch = *(const float4*)(bhl + 64 + jb*4);
#define LWC(C, j) { \
        float zz = fast_sigmoid(axz.C + ahz.C + bz.C + cz.C); \
        float rr = fast_sigmoid(axr.C + ahr.C + br.C + cr.C); \
        float cc = fast_tanh(axh.C + bhi.C + rr * (ahh.C + ch.C)); \
        float ho = h[jb*4+j]; \
        hn[jb*4+j] = cc + zz * (ho - cc); }
        LWC(x, 0) LWC(y, 1) LWC(z, 2) LWC(w, 3)
#undef LWC
    }
    {
        float4* row = (float4*)(link_state + (size_t)i * DPDIM);
        #pragma unroll
        for (int k4 = 0; k4 < 8; ++k4)
            row[k4] = make_float4(hn[4*k4+0], hn[4*k4+1], hn[4*k4+2], hn[4*k4+3]);
    }
}

// ---------------- readout: register-tiled 8x8, r1 k-major + XOR swizzle ----
// block = 256 threads, 64 links. thread: cg = t&31 (8 cols), lg = t>>5 (8 links).
__device__ __forceinline__ int r1slot(int c, int i4) {
    return c*17 + (i4 ^ ((c >> 3) & 15));    // float4 slots, bank-swizzled
}

__global__ __launch_bounds__(256, 2) void readout_kernel(
    const float* __restrict__ link_state,
    const float* __restrict__ W1, const float* __restrict__ b1,
    const float* __restrict__ W2, const float* __restrict__ b2,
    const float* __restrict__ W3, const float* __restrict__ b3,
    float* __restrict__ out, int n_links)
{
    __shared__ __align__(16) float s_r1[256*17*4];   // 68 KB, swizzled float4 slots
    __shared__ __align__(16) float s_aux[32*68];     // 8.7 KB: ls (k-major), then s_red
    int t = threadIdx.x;
    int cg = t & 31, lg = t >> 5;
    int c0 = cg * 8, i0 = lg * 8;
    int l0 = blockIdx.x * 64;
    int nl = n_links - l0; if (nl > 64) nl = 64;

    // ---- stage ls k-major: s_aux[k*68 + i] ----
    {
        int li = t >> 2;              // 0..63
        int k0 = (t & 3) * 8;         // 0,8,16,24
        float4 v0 = {0,0,0,0}, v1 = {0,0,0,0};
        if (li < nl) {
            const float4* row = (const float4*)(link_state + (size_t)(l0+li) * DPDIM);
            v0 = row[k0/4]; v1 = row[k0/4 + 1];
        }
        s_aux[(k0+0)*68 + li] = v0.x; s_aux[(k0+1)*68 + li] = v0.y;
        s_aux[(k0+2)*68 + li] = v0.z; s_aux[(k0+3)*68 + li] = v0.w;
        s_aux[(k0+4)*68 + li] = v1.x; s_aux[(k0+5)*68 + li] = v1.y;
        s_aux[(k0+6)*68 + li] = v1.z; s_aux[(k0+7)*68 + li] = v1.w;
    }
    __syncthreads();

    // ---- phase A: r1 tile [8 cols][8 links] ----
    float r1t[8][8];
    #pragma unroll
    for (int ci = 0; ci < 8; ++ci)
        #pragma unroll
        for (int li = 0; li < 8; ++li) r1t[ci][li] = 0.f;
    for (int k = 0; k < DPDIM; ++k) {
        float a[8], wv[8];
        *(float4*)(a)   = *(const float4*)(&s_aux[k*68 + i0]);
        *(float4*)(a+4) = *(const float4*)(&s_aux[k*68 + i0 + 4]);
        *(float4*)(wv)   = *(const float4*)(W1 + k*RUNITS + c0);
        *(float4*)(wv+4) = *(const float4*)(W1 + k*RUNITS + c0 + 4);
        #pragma unroll
        for (int ci = 0; ci < 8; ++ci)
            #pragma unroll
            for (int li = 0; li < 8; ++li)
                r1t[ci][li] = fmaf(wv[ci], a[li], r1t[ci][li]);
    }
    {
        float4* s_r1v = (float4*)s_r1;
        #pragma unroll
        for (int ci = 0; ci < 8; ++ci) {
            float bb = b1[c0 + ci];
            float4 lo = make_float4(fmaxf(r1t[ci][0]+bb, 0.f), fmaxf(r1t[ci][1]+bb, 0.f),
                                    fmaxf(r1t[ci][2]+bb, 0.f), fmaxf(r1t[ci][3]+bb, 0.f));
            float4 hi = make_float4(fmaxf(r1t[ci][4]+bb, 0.f), fmaxf(r1t[ci][5]+bb, 0.f),
                                    fmaxf(r1t[ci][6]+bb, 0.f), fmaxf(r1t[ci][7]+bb, 0.f));
            s_r1v[r1slot(c0+ci, 2*lg)]     = lo;
            s_r1v[r1slot(c0+ci, 2*lg + 1)] = hi;
        }
    }
    __syncthreads();

    // ---- phase B: r2 tile += r1[k][links] * W2[k][cols] ----
    float acc[8][8];
    #pragma unroll
    for (int ci = 0; ci < 8; ++ci)
        #pragma unroll
        for (int li = 0; li < 8; ++li) acc[ci][li] = 0.f;
    const float4* s_r1v = (const float4*)s_r1;
    #pragma unroll 1
    for (int k = 0; k < RUNITS; k += 2) {
        #pragma unroll
        for (int kk = 0; kk < 2; ++kk) {
            float a[8], wv[8];
            *(float4*)(a)    = s_r1v[r1slot(k+kk, 2*lg)];
            *(float4*)(a+4)  = s_r1v[r1slot(k+kk, 2*lg + 1)];
            *(float4*)(wv)   = *(const float4*)(W2 + (k+kk)*RUNITS + c0);
            *(float4*)(wv+4) = *(const float4*)(W2 + (k+kk)*RUNITS + c0 + 4);
            #pragma unroll
            for (int ci = 0; ci < 8; ++ci)
                #pragma unroll
                for (int li = 0; li < 8; ++li)
                    acc[ci][li] = fmaf(wv[ci], a[li], acc[ci][li]);
        }
    }

    // ---- phase C: relu(acc + b2) * w3, partial-reduce over this thread's cols
    float b2v[8], w3v[8];
    *(float4*)(b2v)   = *(const float4*)(b2 + c0);
    *(float4*)(b2v+4) = *(const float4*)(b2 + c0 + 4);
    *(float4*)(w3v)   = *(const float4*)(W3 + c0);
    *(float4*)(w3v+4) = *(const float4*)(W3 + c0 + 4);
    float psum[8];
    #pragma unroll
    for (int li = 0; li < 8; ++li) psum[li] = 0.f;
    #pragma unroll
    for (int ci = 0; ci < 8; ++ci)
        #pragma unroll
        for (int li = 0; li < 8; ++li)
            psum[li] = fmaf(fmaxf(acc[ci][li] + b2v[ci], 0.f), w3v[ci], psum[li]);
    __syncthreads();                 // s_aux (ls) dead; reuse as s_red[64][33]
    #pragma unroll
    for (int li = 0; li < 8; ++li)
        s_aux[(i0 + li)*33 + cg] = psum[li];
    __syncthreads();
    if (t < nl) {
        float ssum = 0.f;
        #pragma unroll
        for (int j = 0; j < 32; ++j) ssum += s_aux[t*33 + j];
        out[l0 + t] = b3[0] + ssum;
    }
}

// ---------------- launch ----------------
extern "C" void kernel_launch(void* const* d_in, const int* in_sizes, int n_in,
                              void* d_out, int out_size, void* d_ws, size_t ws_size,
                              hipStream_t stream)
{
    const float* traffic  = (const float*)d_in[0];
    const float* packets  = (const float*)d_in[1];
    const float* eqlam    = (const float*)d_in[2];
    const float* avgpkt   = (const float*)d_in[3];
    const float* capacity = (const float*)d_in[4];
    const float* queues   = (const float*)d_in[5];
    const int* link_to_path = (const int*)d_in[6];
    const float* Wp  = (const float*)d_in[13];
    const float* Up  = (const float*)d_in[14];
    const float* bip = (const float*)d_in[15];
    const float* bhp = (const float*)d_in[16];
    const float* Wl  = (const float*)d_in[17];
    const float* Ul  = (const float*)d_in[18];
    const float* bil = (const float*)d_in[19];
    const float* bhl = (const float*)d_in[20];
    const float* W1  = (const float*)d_in[21];
    const float* b1  = (const float*)d_in[22];
    const float* W2  = (const float*)d_in[23];
    const float* b2  = (const float*)d_in[24];
    const float* W3  = (const float*)d_in[25];
    const float* b3  = (const float*)d_in[26];
    const int n_paths = in_sizes[0];     // 100000
    const int n_links = in_sizes[4];     // 20000
    const int n_ent   = in_sizes[6];     // 800000

    char* ws = (char*)d_ws;
    size_t off = 0;
    auto salloc = [&](size_t bytes) -> void* {
        void* p = ws + off;
        off += (bytes + 255) & ~size_t(255);
        return p;
    };
    float* path_state = (float*)salloc((size_t)n_paths * DPDIM * 4);
    float* link_state = (float*)salloc((size_t)n_links * DPDIM * 4);
    // Gi (gate_pre -> path_kernel) then dead; path_sum (seg_sum -> link_kernel)
    // never overlaps in time; alias.
    float* Gi         = (float*)salloc((size_t)n_links * GCOLS * 4);
    float* path_sum   = Gi;
    float* UpT   = (float*)salloc((size_t)8 * 32 * 12 * 4);
    float* WpT   = (float*)salloc((size_t)8 * 32 * 12 * 4);
    float* WlT   = (float*)salloc((size_t)8 * 32 * 12 * 4);
    float* UlT   = (float*)salloc((size_t)8 * 32 * 12 * 4);
    int* nzf     = (int*)salloc((size_t)n_links * 4);
    int* counts  = (int*)salloc((size_t)n_links * 4);
    int* offsets = (int*)salloc((size_t)(n_links + 1) * 4);
    int* cursor  = (int*)salloc((size_t)n_links * 4);
    int* entries = (int*)salloc((size_t)n_ent * 4);
    (void)ws_size; (void)n_in; (void)out_size;

    int gmax = ( (n_paths > n_links ? n_paths : n_links) + 255 ) / 256;
    zero_counts_kernel<<<(n_links + 255)/256, 256, 0, stream>>>(counts, n_links);
    init_kernel<<<gmax, 256, 0, stream>>>(traffic, packets, eqlam, avgpkt,
                                          capacity, queues, path_state, link_state,
                                          n_paths, n_links);
    transpose_w_kernel<<<(8*32*12 + 255)/256, 256, 0, stream>>>(Up, UpT);
    transpose_w_kernel<<<(8*32*12 + 255)/256, 256, 0, stream>>>(Wp, WpT);
    transpose_w_kernel<<<(8*32*12 + 255)/256, 256, 0, stream>>>(Wl, WlT);
    transpose_w_kernel<<<(8*32*12 + 255)/256, 256, 0, stream>>>(Ul, UlT);
    hist_kernel<<<(n_ent + 255)/256, 256, 0, stream>>>(link_to_path, counts, n_ent);
    scan_kernel<<<1, 1024, 0, stream>>>(counts, offsets, cursor, n_links);
    fill_kernel<<<(n_ent + 255)/256, 256, 0, stream>>>(link_to_path, cursor, entries, n_ent);

    int gl = (n_links + 63) / 64;
    for (int it = 0; it < T_ITERS; ++it) {
        gate_pre_kernel<<<gl, 64, 0, stream>>>(
            link_state, WpT, bip, bhp, Gi, nzf, n_links);
        path_kernel<<<(n_paths + 63)/64, 64, 0, stream>>>(
            Gi, nzf, path_state, link_to_path, UpT, bhp, n_paths);
        seg_sum_kernel<<<(n_links + 7)/8, 256, 0, stream>>>(
            path_state, offsets, entries, path_sum, n_links);
        link_kernel<<<gl, 64, 0, stream>>>(
            path_sum, link_state, WlT, UlT, bil, bhl, n_links);
    }
    readout_kernel<<<(n_links + 63)/64, 256, 0, stream>>>(
        link_state, W1, b1, W2, b2, W3, b3, (float*)d_out, n_links);
}

// Round 6
// 2365.247 us; speedup vs baseline: 1.7432x; 1.7432x over previous
//
#include <hip/hip_runtime.h>

#define DPDIM 32         // path/link state dim
#define GCOLS 96         // 3*DPDIM gate columns
#define PLEN 8
#define T_ITERS 8
#define RUNITS 256

// ---------------- fast activations (v_exp_f32 + v_rcp_f32) ----------------
__device__ __forceinline__ float fast_sigmoid(float a) {
    return __builtin_amdgcn_rcpf(1.0f + __expf(-a));
}
__device__ __forceinline__ float fast_tanh(float a) {
    return 1.0f - 2.0f * __builtin_amdgcn_rcpf(1.0f + __expf(2.0f * a));
}

#define ACC4F(A, s, V) \
    A.x = fmaf((s), (V).x, A.x); A.y = fmaf((s), (V).y, A.y); \
    A.z = fmaf((s), (V).z, A.z); A.w = fmaf((s), (V).w, A.w);

// ---------------- init states ----------------
__global__ __launch_bounds__(256) void init_kernel(
    const float* __restrict__ traffic, const float* __restrict__ packets,
    const float* __restrict__ eqlam, const float* __restrict__ avgpkt,
    const float* __restrict__ capacity, const float* __restrict__ queues,
    float* __restrict__ path_state, float* __restrict__ link_state,
    int n_paths, int n_links)
{
    int i = blockIdx.x * 256 + threadIdx.x;
    if (i < n_paths) {
        float4* row = (float4*)(path_state + (size_t)i * DPDIM);
        row[0] = make_float4(traffic[i], packets[i], eqlam[i], avgpkt[i]);
        float4 z = make_float4(0.f, 0.f, 0.f, 0.f);
        #pragma unroll
        for (int k = 1; k < 8; ++k) row[k] = z;
    }
    if (i < n_links) {
        float4* row = (float4*)(link_state + (size_t)i * DPDIM);
        row[0] = make_float4(capacity[i], queues[i], 0.f, 0.f);
        float4 z = make_float4(0.f, 0.f, 0.f, 0.f);
        #pragma unroll
        for (int k = 1; k < 8; ++k) row[k] = z;
    }
}

// ---------------- weight transpose: W[k][96] -> WT[jb][k][12] --------------
__global__ __launch_bounds__(256) void transpose_w_kernel(
    const float* __restrict__ W, float* __restrict__ WT)
{
    int i = blockIdx.x * 256 + threadIdx.x;
    if (i >= 8*32*12) return;
    int idx = i % 12;
    int k   = (i / 12) % 32;
    int jb  = i / (12*32);
    int gate = idx >> 2, c = idx & 3;
    WT[i] = W[k*GCOLS + gate*32 + jb*4 + c];
}

// ---------------- CSR build ----------------
__global__ __launch_bounds__(256) void zero_counts_kernel(int* __restrict__ counts, int n) {
    int i = blockIdx.x * 256 + threadIdx.x;
    if (i < n) counts[i] = 0;
}
__global__ __launch_bounds__(256) void hist_kernel(
    const int* __restrict__ link_to_path, int* __restrict__ counts, int n) {
    int i = blockIdx.x * 256 + threadIdx.x;
    if (i < n) atomicAdd(&counts[link_to_path[i]], 1);
}
__global__ __launch_bounds__(1024) void scan_kernel(
    const int* __restrict__ counts, int* __restrict__ offsets,
    int* __restrict__ cursor, int n)
{
    __shared__ int s[1024];
    int t = threadIdx.x;
    int chunk = (n + 1023) >> 10;
    int lo = t * chunk;
    int hi = lo + chunk; if (hi > n) hi = n;
    int local = 0;
    for (int i = lo; i < hi; ++i) local += counts[i];
    s[t] = local;
    __syncthreads();
    for (int d = 1; d < 1024; d <<= 1) {
        int v = (t >= d) ? s[t - d] : 0;
        __syncthreads();
        s[t] += v;
        __syncthreads();
    }
    int base = (t > 0) ? s[t - 1] : 0;
    for (int i = lo; i < hi; ++i) {
        offsets[i] = base; cursor[i] = base; base += counts[i];
    }
    if (t == 1023) offsets[n] = s[1023];
}
__global__ __launch_bounds__(256) void fill_kernel(
    const int* __restrict__ link_to_path, int* __restrict__ cursor,
    int* __restrict__ entries, int n) {
    int e = blockIdx.x * 256 + threadIdx.x;
    if (e < n) {
        int l = link_to_path[e];
        int pos = atomicAdd(&cursor[l], 1);
        entries[pos] = e >> 3;   // path id (PLEN == 8)
    }
}

// ---------------- gate precompute (paths): G = ls@Wp + bip (+bhp for z,r) --
__global__ __launch_bounds__(64) void gate_pre_kernel(
    const float* __restrict__ X, const float* __restrict__ WT,
    const float* __restrict__ bi, const float* __restrict__ bh,
    float* __restrict__ G, int* __restrict__ nzf, int n)
{
    int i = blockIdx.x * 64 + threadIdx.x;
    if (i >= n) return;
    float x[DPDIM];
    bool nz = false;
    const float4* row = (const float4*)(X + (size_t)i * DPDIM);
    #pragma unroll
    for (int k4 = 0; k4 < 8; ++k4) {
        float4 v = row[k4];
        x[4*k4+0]=v.x; x[4*k4+1]=v.y; x[4*k4+2]=v.z; x[4*k4+3]=v.w;
        nz = nz || (v.x != 0.f) || (v.y != 0.f) || (v.z != 0.f) || (v.w != 0.f);
    }
    float* Gp = G + (size_t)i * GCOLS;
    #pragma unroll 1
    for (int jb = 0; jb < 8; ++jb) {
        float4 az = {0.f,0.f,0.f,0.f}, ar = {0.f,0.f,0.f,0.f}, ah = {0.f,0.f,0.f,0.f};
        const float* w = WT + jb*(32*12);
        #pragma unroll
        for (int k = 0; k < DPDIM; ++k) {
            const float xk = x[k];
            ACC4F(az, xk, *(const float4*)(w));
            ACC4F(ar, xk, *(const float4*)(w + 4));
            ACC4F(ah, xk, *(const float4*)(w + 8));
            w += 12;
        }
        const float4 bz = *(const float4*)(bi + jb*4);
        const float4 br = *(const float4*)(bi + 32 + jb*4);
        const float4 bhi = *(const float4*)(bi + 64 + jb*4);
        const float4 cz = *(const float4*)(bh + jb*4);
        const float4 cr = *(const float4*)(bh + 32 + jb*4);
        *(float4*)(Gp + jb*4)      = make_float4(az.x+bz.x+cz.x, az.y+bz.y+cz.y,
                                                 az.z+bz.z+cz.z, az.w+bz.w+cz.w);
        *(float4*)(Gp + 32 + jb*4) = make_float4(ar.x+br.x+cr.x, ar.y+br.y+cr.y,
                                                 ar.z+br.z+cr.z, ar.w+br.w+cr.w);
        *(float4*)(Gp + 64 + jb*4) = make_float4(ah.x+bhi.x, ah.y+bhi.y,
                                                 ah.z+bhi.z, ah.w+bhi.w);
    }
    nzf[i] = nz ? 1 : 0;
}

// ---------------- path GRU: hybrid reg/LDS recurrent state -----------------
// h in REGISTERS for the statically-unrolled k-loop (pure FMA, no LDS);
// the dynamically-indexed accesses (ho read, hnew write per jb) go through
// per-thread LDS columns, ping-pong buffered, no barriers. jb loop stays
// dynamic so Gi gather results never pile up in registers (round-5 spill).
__global__ __launch_bounds__(64, 1) void path_kernel(
    const float* __restrict__ Gi, const int* __restrict__ nzf,
    float* __restrict__ path_state, const int* __restrict__ link_to_path,
    const float* __restrict__ UpT, const float* __restrict__ bhp, int n_paths)
{
    __shared__ float hbuf[2*DPDIM*64];    // 16 KB, [buf][k][lane]
    int t = threadIdx.x;
    int p = blockIdx.x * 64 + t;
    bool act = p < n_paths;
    int pp = act ? p : (n_paths - 1);
    float h[DPDIM];
    {
        const float4* row = (const float4*)(path_state + (size_t)pp * DPDIM);
        #pragma unroll
        for (int k4 = 0; k4 < 8; ++k4) {
            float4 v = row[k4];
            h[4*k4+0]=v.x; h[4*k4+1]=v.y; h[4*k4+2]=v.z; h[4*k4+3]=v.w;
            hbuf[(4*k4+0)*64 + t] = v.x; hbuf[(4*k4+1)*64 + t] = v.y;
            hbuf[(4*k4+2)*64 + t] = v.z; hbuf[(4*k4+3)*64 + t] = v.w;
        }
    }
    int cur = 0;
    int l = link_to_path[pp*PLEN];
    #pragma unroll 1
    for (int s = 0; s < PLEN; ++s) {
        int l_next = (s+1 < PLEN) ? link_to_path[pp*PLEN + s + 1] : 0;
        bool nz = act && (nzf[l] != 0);
        const float* G = Gi + (size_t)l * GCOLS;
        float* hold = hbuf + cur*(DPDIM*64);
        float* hnew = hbuf + (cur^1)*(DPDIM*64);
        #pragma unroll 1
        for (int jb = 0; jb < 8; ++jb) {
            // gather loads: issued at jb top, consumed after 768 FMA-cycles
            const float4 giz = *(const float4*)(G + jb*4);
            const float4 gir = *(const float4*)(G + 32 + jb*4);
            const float4 gih = *(const float4*)(G + 64 + jb*4);
            float4 az = {0.f,0.f,0.f,0.f}, ar = {0.f,0.f,0.f,0.f}, ah = {0.f,0.f,0.f,0.f};
            const float* w = UpT + jb*(32*12);
            #pragma unroll
            for (int k = 0; k < DPDIM; ++k) {
                ACC4F(az, h[k], *(const float4*)(w));
                ACC4F(ar, h[k], *(const float4*)(w + 4));
                ACC4F(ah, h[k], *(const float4*)(w + 8));
                w += 12;
            }
            const float4 bhh = *(const float4*)(bhp + 64 + jb*4);   // uniform
#define PWC(C, j) { \
            float zz = fast_sigmoid(az.C + giz.C); \
            float rr = fast_sigmoid(ar.C + gir.C); \
            float cc = fast_tanh(gih.C + rr * (ah.C + bhh.C)); \
            float ho = hold[(jb*4+j)*64 + t]; \
            hnew[(jb*4+j)*64 + t] = nz ? (cc + zz * (ho - cc)) : ho; }
            PWC(x, 0) PWC(y, 1) PWC(z, 2) PWC(w, 3)
#undef PWC
        }
        #pragma unroll
        for (int k = 0; k < DPDIM; ++k) h[k] = hnew[k*64 + t];
        cur ^= 1;
        l = l_next;
    }
    if (act) {
        float4* row = (float4*)(path_state + (size_t)p * DPDIM);
        #pragma unroll
        for (int k4 = 0; k4 < 8; ++k4)
            row[k4] = make_float4(h[4*k4+0], h[4*k4+1], h[4*k4+2], h[4*k4+3]);
    }
}

// ---------------- segment sum: float4 gather, 8 lanes per link -------------
__global__ __launch_bounds__(64) void seg_sum_kernel(
    const float* __restrict__ path_state, const int* __restrict__ offsets,
    const int* __restrict__ entries, float* __restrict__ path_sum, int n_links)
{
    int t = threadIdx.x;
    int d4 = t & 7, li = t >> 3;        // 8 links per block, 8 float4-lanes each
    int l = blockIdx.x * 8 + li;
    if (l >= n_links) return;
    int beg = offsets[l], end = offsets[l+1];
    const float4* P = (const float4*)path_state;
    float4 a0 = {0.f,0.f,0.f,0.f}, a1 = {0.f,0.f,0.f,0.f};
    int q = beg;
    for (; q + 1 < end; q += 2) {
        int p0 = entries[q], p1 = entries[q+1];
        float4 v0 = P[(size_t)p0 * 8 + d4];
        float4 v1 = P[(size_t)p1 * 8 + d4];
        a0.x += v0.x; a0.y += v0.y; a0.z += v0.z; a0.w += v0.w;
        a1.x += v1.x; a1.y += v1.y; a1.z += v1.z; a1.w += v1.w;
    }
    if (q < end) {
        float4 v = P[(size_t)entries[q] * 8 + d4];
        a0.x += v.x; a0.y += v.y; a0.z += v.z; a0.w += v.w;
    }
    ((float4*)path_sum)[(size_t)l * 8 + d4] =
        make_float4(a0.x + a1.x, a0.y + a1.y, a0.z + a1.z, a0.w + a1.w);
}

// ---------------- fused link GRU: x,h in regs, ho via LDS, stream stores ---
__global__ __launch_bounds__(64, 1) void link_kernel(
    const float* __restrict__ path_sum, float* __restrict__ link_state,
    const float* __restrict__ WlT, const float* __restrict__ UlT,
    const float* __restrict__ bil, const float* __restrict__ bhl, int n)
{
    __shared__ float hbuf[DPDIM*64];      // 8 KB, [k][lane]
    int t = threadIdx.x;
    int i = blockIdx.x * 64 + t;
    bool act = i < n;
    int ii = act ? i : (n - 1);
    float x[DPDIM], h[DPDIM];
    {
        const float4* xrow = (const float4*)(path_sum + (size_t)ii * DPDIM);
        const float4* hrow = (const float4*)(link_state + (size_t)ii * DPDIM);
        #pragma unroll
        for (int k4 = 0; k4 < 8; ++k4) {
            float4 u = xrow[k4];
            x[4*k4+0]=u.x; x[4*k4+1]=u.y; x[4*k4+2]=u.z; x[4*k4+3]=u.w;
            float4 v = hrow[k4];
            h[4*k4+0]=v.x; h[4*k4+1]=v.y; h[4*k4+2]=v.z; h[4*k4+3]=v.w;
            hbuf[(4*k4+0)*64 + t] = v.x; hbuf[(4*k4+1)*64 + t] = v.y;
            hbuf[(4*k4+2)*64 + t] = v.z; hbuf[(4*k4+3)*64 + t] = v.w;
        }
    }
    float4* orow = (float4*)(link_state + (size_t)i * DPDIM);
    #pragma unroll 1
    for (int jb = 0; jb < 8; ++jb) {
        float4 axz = {0.f,0.f,0.f,0.f}, axr = {0.f,0.f,0.f,0.f}, axh = {0.f,0.f,0.f,0.f};
        float4 ahz = {0.f,0.f,0.f,0.f}, ahr = {0.f,0.f,0.f,0.f}, ahh = {0.f,0.f,0.f,0.f};
        const float* wl = WlT + jb*(32*12);
        const float* ul = UlT + jb*(32*12);
        #pragma unroll
        for (int k = 0; k < DPDIM; ++k) {
            ACC4F(axz, x[k], *(const float4*)(wl));
            ACC4F(axr, x[k], *(const float4*)(wl + 4));
            ACC4F(axh, x[k], *(const float4*)(wl + 8));
            ACC4F(ahz, h[k], *(const float4*)(ul));
            ACC4F(ahr, h[k], *(const float4*)(ul + 4));
            ACC4F(ahh, h[k], *(const float4*)(ul + 8));
            wl += 12; ul += 12;
        }
        const float4 bz = *(const float4*)(bil + jb*4);
        const float4 br = *(const float4*)(bil + 32 + jb*4);
        const float4 bhi = *(const float4*)(bil + 64 + jb*4);
        const float4 cz = *(const float4*)(bhl + jb*4);
        const float4 cr = *(const float4*)(bhl + 32 + jb*4);
        const float4 ch = *(const float4*)(bhl + 64 + jb*4);
        float4 hn;
#define LWC(C, j) { \
        float zz = fast_sigmoid(axz.C + ahz.C + bz.C + cz.C); \
        float rr = fast_sigmoid(axr.C + ahr.C + br.C + cr.C); \
        float cc = fast_tanh(axh.C + bhi.C + rr * (ahh.C + ch.C)); \
        float ho = hbuf[(jb*4+j)*64 + t]; \
        hn.C = cc + zz * (ho - cc); }
        LWC(x, 0) LWC(y, 1) LWC(z, 2) LWC(w, 3)
#undef LWC
        if (act) orow[jb] = hn;
    }
}

// ---------------- readout: register-tiled 8x8, r1 k-major + XOR swizzle ----
__device__ __forceinline__ int r1slot(int c, int i4) {
    return c*17 + (i4 ^ ((c >> 3) & 15));    // float4 slots, bank-swizzled
}

__global__ __launch_bounds__(256, 2) void readout_kernel(
    const float* __restrict__ link_state,
    const float* __restrict__ W1, const float* __restrict__ b1,
    const float* __restrict__ W2, const float* __restrict__ b2,
    const float* __restrict__ W3, const float* __restrict__ b3,
    float* __restrict__ out, int n_links)
{
    __shared__ __align__(16) float s_r1[256*17*4];   // 68 KB, swizzled float4 slots
    __shared__ __align__(16) float s_aux[32*68];     // 8.7 KB: ls (k-major), then s_red
    int t = threadIdx.x;
    int cg = t & 31, lg = t >> 5;
    int c0 = cg * 8, i0 = lg * 8;
    int l0 = blockIdx.x * 64;
    int nl = n_links - l0; if (nl > 64) nl = 64;

    {
        int li = t >> 2;              // 0..63
        int k0 = (t & 3) * 8;         // 0,8,16,24
        float4 v0 = {0,0,0,0}, v1 = {0,0,0,0};
        if (li < nl) {
            const float4* row = (const float4*)(link_state + (size_t)(l0+li) * DPDIM);
            v0 = row[k0/4]; v1 = row[k0/4 + 1];
        }
        s_aux[(k0+0)*68 + li] = v0.x; s_aux[(k0+1)*68 + li] = v0.y;
        s_aux[(k0+2)*68 + li] = v0.z; s_aux[(k0+3)*68 + li] = v0.w;
        s_aux[(k0+4)*68 + li] = v1.x; s_aux[(k0+5)*68 + li] = v1.y;
        s_aux[(k0+6)*68 + li] = v1.z; s_aux[(k0+7)*68 + li] = v1.w;
    }
    __syncthreads();

    float r1t[8][8];
    #pragma unroll
    for (int ci = 0; ci < 8; ++ci)
        #pragma unroll
        for (int li = 0; li < 8; ++li) r1t[ci][li] = 0.f;
    for (int k = 0; k < DPDIM; ++k) {
        float a[8], wv[8];
        *(float4*)(a)   = *(const float4*)(&s_aux[k*68 + i0]);
        *(float4*)(a+4) = *(const float4*)(&s_aux[k*68 + i0 + 4]);
        *(float4*)(wv)   = *(const float4*)(W1 + k*RUNITS + c0);
        *(float4*)(wv+4) = *(const float4*)(W1 + k*RUNITS + c0 + 4);
        #pragma unroll
        for (int ci = 0; ci < 8; ++ci)
            #pragma unroll
            for (int li = 0; li < 8; ++li)
                r1t[ci][li] = fmaf(wv[ci], a[li], r1t[ci][li]);
    }
    {
        float4* s_r1v = (float4*)s_r1;
        #pragma unroll
        for (int ci = 0; ci < 8; ++ci) {
            float bb = b1[c0 + ci];
            float4 lo = make_float4(fmaxf(r1t[ci][0]+bb, 0.f), fmaxf(r1t[ci][1]+bb, 0.f),
                                    fmaxf(r1t[ci][2]+bb, 0.f), fmaxf(r1t[ci][3]+bb, 0.f));
            float4 hi = make_float4(fmaxf(r1t[ci][4]+bb, 0.f), fmaxf(r1t[ci][5]+bb, 0.f),
                                    fmaxf(r1t[ci][6]+bb, 0.f), fmaxf(r1t[ci][7]+bb, 0.f));
            s_r1v[r1slot(c0+ci, 2*lg)]     = lo;
            s_r1v[r1slot(c0+ci, 2*lg + 1)] = hi;
        }
    }
    __syncthreads();

    float acc[8][8];
    #pragma unroll
    for (int ci = 0; ci < 8; ++ci)
        #pragma unroll
        for (int li = 0; li < 8; ++li) acc[ci][li] = 0.f;
    const float4* s_r1v = (const float4*)s_r1;
    #pragma unroll 1
    for (int k = 0; k < RUNITS; k += 2) {
        #pragma unroll
        for (int kk = 0; kk < 2; ++kk) {
            float a[8], wv[8];
            *(float4*)(a)    = s_r1v[r1slot(k+kk, 2*lg)];
            *(float4*)(a+4)  = s_r1v[r1slot(k+kk, 2*lg + 1)];
            *(float4*)(wv)   = *(const float4*)(W2 + (k+kk)*RUNITS + c0);
            *(float4*)(wv+4) = *(const float4*)(W2 + (k+kk)*RUNITS + c0 + 4);
            #pragma unroll
            for (int ci = 0; ci < 8; ++ci)
                #pragma unroll
                for (int li = 0; li < 8; ++li)
                    acc[ci][li] = fmaf(wv[ci], a[li], acc[ci][li]);
        }
    }

    float b2v[8], w3v[8];
    *(float4*)(b2v)   = *(const float4*)(b2 + c0);
    *(float4*)(b2v+4) = *(const float4*)(b2 + c0 + 4);
    *(float4*)(w3v)   = *(const float4*)(W3 + c0);
    *(float4*)(w3v+4) = *(const float4*)(W3 + c0 + 4);
    float psum[8];
    #pragma unroll
    for (int li = 0; li < 8; ++li) psum[li] = 0.f;
    #pragma unroll
    for (int ci = 0; ci < 8; ++ci)
        #pragma unroll
        for (int li = 0; li < 8; ++li)
            psum[li] = fmaf(fmaxf(acc[ci][li] + b2v[ci], 0.f), w3v[ci], psum[li]);
    __syncthreads();                 // s_aux (ls) dead; reuse as s_red[64][33]
    #pragma unroll
    for (int li = 0; li < 8; ++li)
        s_aux[(i0 + li)*33 + cg] = psum[li];
    __syncthreads();
    if (t < nl) {
        float ssum = 0.f;
        #pragma unroll
        for (int j = 0; j < 32; ++j) ssum += s_aux[t*33 + j];
        out[l0 + t] = b3[0] + ssum;
    }
}

// ---------------- launch ----------------
extern "C" void kernel_launch(void* const* d_in, const int* in_sizes, int n_in,
                              void* d_out, int out_size, void* d_ws, size_t ws_size,
                              hipStream_t stream)
{
    const float* traffic  = (const float*)d_in[0];
    const float* packets  = (const float*)d_in[1];
    const float* eqlam    = (const float*)d_in[2];
    const float* avgpkt   = (const float*)d_in[3];
    const float* capacity = (const float*)d_in[4];
    const float* queues   = (const float*)d_in[5];
    const int* link_to_path = (const int*)d_in[6];
    const float* Wp  = (const float*)d_in[13];
    const float* Up  = (const float*)d_in[14];
    const float* bip = (const float*)d_in[15];
    const float* bhp = (const float*)d_in[16];
    const float* Wl  = (const float*)d_in[17];
    const float* Ul  = (const float*)d_in[18];
    const float* bil = (const float*)d_in[19];
    const float* bhl = (const float*)d_in[20];
    const float* W1  = (const float*)d_in[21];
    const float* b1  = (const float*)d_in[22];
    const float* W2  = (const float*)d_in[23];
    const float* b2  = (const float*)d_in[24];
    const float* W3  = (const float*)d_in[25];
    const float* b3  = (const float*)d_in[26];
    const int n_paths = in_sizes[0];     // 100000
    const int n_links = in_sizes[4];     // 20000
    const int n_ent   = in_sizes[6];     // 800000

    char* ws = (char*)d_ws;
    size_t off = 0;
    auto salloc = [&](size_t bytes) -> void* {
        void* p = ws + off;
        off += (bytes + 255) & ~size_t(255);
        return p;
    };
    float* path_state = (float*)salloc((size_t)n_paths * DPDIM * 4);
    float* link_state = (float*)salloc((size_t)n_links * DPDIM * 4);
    float* Gi         = (float*)salloc((size_t)n_links * GCOLS * 4);
    float* path_sum   = Gi;              // time-disjoint, alias
    float* UpT   = (float*)salloc((size_t)8 * 32 * 12 * 4);
    float* WpT   = (float*)salloc((size_t)8 * 32 * 12 * 4);
    float* WlT   = (float*)salloc((size_t)8 * 32 * 12 * 4);
    float* UlT   = (float*)salloc((size_t)8 * 32 * 12 * 4);
    int* nzf     = (int*)salloc((size_t)n_links * 4);
    int* counts  = (int*)salloc((size_t)n_links * 4);
    int* offsets = (int*)salloc((size_t)(n_links + 1) * 4);
    int* cursor  = (int*)salloc((size_t)n_links * 4);
    int* entries = (int*)salloc((size_t)n_ent * 4);
    (void)ws_size; (void)n_in; (void)out_size;

    int gmax = ( (n_paths > n_links ? n_paths : n_links) + 255 ) / 256;
    zero_counts_kernel<<<(n_links + 255)/256, 256, 0, stream>>>(counts, n_links);
    init_kernel<<<gmax, 256, 0, stream>>>(traffic, packets, eqlam, avgpkt,
                                          capacity, queues, path_state, link_state,
                                          n_paths, n_links);
    transpose_w_kernel<<<(8*32*12 + 255)/256, 256, 0, stream>>>(Up, UpT);
    transpose_w_kernel<<<(8*32*12 + 255)/256, 256, 0, stream>>>(Wp, WpT);
    transpose_w_kernel<<<(8*32*12 + 255)/256, 256, 0, stream>>>(Wl, WlT);
    transpose_w_kernel<<<(8*32*12 + 255)/256, 256, 0, stream>>>(Ul, UlT);
    hist_kernel<<<(n_ent + 255)/256, 256, 0, stream>>>(link_to_path, counts, n_ent);
    scan_kernel<<<1, 1024, 0, stream>>>(counts, offsets, cursor, n_links);
    fill_kernel<<<(n_ent + 255)/256, 256, 0, stream>>>(link_to_path, cursor, entries, n_ent);

    int gl = (n_links + 63) / 64;
    for (int it = 0; it < T_ITERS; ++it) {
        gate_pre_kernel<<<gl, 64, 0, stream>>>(
            link_state, WpT, bip, bhp, Gi, nzf, n_links);
        path_kernel<<<(n_paths + 63)/64, 64, 0, stream>>>(
            Gi, nzf, path_state, link_to_path, UpT, bhp, n_paths);
        seg_sum_kernel<<<(n_links + 7)/8, 64, 0, stream>>>(
            path_state, offsets, entries, path_sum, n_links);
        link_kernel<<<gl, 64, 0, stream>>>(
            path_sum, link_state, WlT, UlT, bil, bhl, n_links);
    }
    readout_kernel<<<(n_links + 63)/64, 256, 0, stream>>>(
        link_state, W1, b1, W2, b2, W3, b3, (float*)d_out, n_links);
}